// Round 6
// baseline (523.670 us; speedup 1.0000x reference)
//
#include <hip/hip_runtime.h>

#define N_NODES 50000
#define NEDGE   800000
#define D       128
#define EPS     1e-5f
#define NHALF   ((size_t)N_NODES * 64)

typedef __attribute__((ext_vector_type(8))) short bf16x8;
typedef __attribute__((ext_vector_type(4))) float f32x4;
typedef __attribute__((ext_vector_type(8))) unsigned short u16x8;

// fp32 -> bf16 (RNE) as ushort bits
__device__ inline uint32_t bfhi(float f) {
    uint32_t u = __float_as_uint(f);
    u += 0x7fffu + ((u >> 16) & 1u);
    return u >> 16;
}
__device__ inline float bff(uint32_t h) { return __uint_as_float(h << 16); }

// ---------------- degree count ----------------
__global__ __launch_bounds__(256) void k_deg(const int* __restrict__ dst,
                                             int* __restrict__ degi) {
    int e = blockIdx.x * 256 + threadIdx.x;
    if (e < NEDGE) atomicAdd(&degi[dst[e]], 1);
}

// ---------------- exclusive scan (3 kernels) ----------------
__global__ __launch_bounds__(256) void k_scan1(const int* __restrict__ degi,
                                               int* __restrict__ offs,
                                               int* __restrict__ bsum) {
    __shared__ int s[256];
    int tid = threadIdx.x;
    int i = blockIdx.x * 256 + tid;
    int v = (i < N_NODES) ? degi[i] : 0;
    s[tid] = v;
    __syncthreads();
    for (int d = 1; d < 256; d <<= 1) {
        int t = (tid >= d) ? s[tid - d] : 0;
        __syncthreads();
        s[tid] += t;
        __syncthreads();
    }
    if (i < N_NODES) offs[i] = s[tid] - v;   // exclusive
    if (tid == 255) bsum[blockIdx.x] = s[255];
}

__global__ __launch_bounds__(256) void k_scan2(int* __restrict__ bsum, int nb) {
    __shared__ int s[256];
    int tid = threadIdx.x;
    int v = (tid < nb) ? bsum[tid] : 0;
    s[tid] = v;
    __syncthreads();
    for (int d = 1; d < 256; d <<= 1) {
        int t = (tid >= d) ? s[tid - d] : 0;
        __syncthreads();
        s[tid] += t;
        __syncthreads();
    }
    if (tid < nb) bsum[tid] = s[tid] - v;    // exclusive block offsets
}

__global__ __launch_bounds__(256) void k_scan3(const int* __restrict__ degi,
                                               const int* __restrict__ bsum,
                                               int* __restrict__ offs,
                                               int* __restrict__ cursor,
                                               float* __restrict__ invdeg) {
    int i = blockIdx.x * 256 + threadIdx.x;
    if (i < N_NODES) {
        int o = offs[i] + bsum[blockIdx.x];
        offs[i] = o;
        cursor[i] = o;
        int dg = degi[i];
        invdeg[i] = 1.0f / (float)(dg > 0 ? dg : 1);
    }
    if (i == 0 && blockIdx.x == 0) offs[N_NODES] = NEDGE;
}

// ---------------- CSR bucket fill ----------------
__global__ __launch_bounds__(256) void k_fill(const int* __restrict__ src,
                                              const int* __restrict__ dst,
                                              int* __restrict__ cursor,
                                              int* __restrict__ csr) {
    int e = blockIdx.x * 256 + threadIdx.x;
    if (e < NEDGE) {
        int p = atomicAdd(&cursor[dst[e]], 1);
        csr[p] = src[e];
    }
}

// ---------------- fp32 -> bf16(hi) split planes [2][N][64] ----------------
__global__ __launch_bounds__(256) void k_tobf16(const float* __restrict__ X,
                                                unsigned short* __restrict__ XB) {
    int t = blockIdx.x * 256 + threadIdx.x;
    if (t >= (N_NODES * D) / 8) return;
    int n = t >> 4;
    int c8 = (t & 15) * 8;
    const float* p = X + (size_t)n * D + c8;
    float4 a = *reinterpret_cast<const float4*>(p);
    float4 b = *reinterpret_cast<const float4*>(p + 4);
    u16x8 o;
    o[0] = (unsigned short)bfhi(a.x); o[1] = (unsigned short)bfhi(a.y);
    o[2] = (unsigned short)bfhi(a.z); o[3] = (unsigned short)bfhi(a.w);
    o[4] = (unsigned short)bfhi(b.x); o[5] = (unsigned short)bfhi(b.y);
    o[6] = (unsigned short)bfhi(b.z); o[7] = (unsigned short)bfhi(b.w);
    int half = c8 >> 6;
    *reinterpret_cast<u16x8*>(XB + (size_t)half * NHALF + (size_t)n * 64 + (c8 & 63)) = o;
}

// ---------------- mean aggregation: gather one 64-col half over CSR ----------------
// XCD-sharded: under round-robin bid%8->XCD, bit2 of bid pins XCDs 0-3 to half 0
// and XCDs 4-7 to half 1, halving per-XCD L2 compulsory fill. Correct regardless.
// 32 nodes/block, 8 lanes/node (64 cols = 128B/row = one cache line).
__global__ __launch_bounds__(256) void k_agg(const unsigned short* __restrict__ XB,
                                             const int* __restrict__ offs,
                                             const int* __restrict__ csr,
                                             const float* __restrict__ invdeg,
                                             const float* __restrict__ bnscale,
                                             const float* __restrict__ bnshift,
                                             int useBn,
                                             float* __restrict__ HN) {
    int bid = blockIdx.x;
    int half = (bid >> 2) & 1;
    int nb = (bid >> 3) * 4 + (bid & 3);
    if (nb >= 1563) return;
    int n = nb * 32 + (threadIdx.x >> 3);
    if (n >= N_NODES) return;
    int c = (threadIdx.x & 7) * 8;        // col within half
    int gc = half * 64 + c;               // global col
    const unsigned short* XH = XB + (size_t)half * NHALF;

    float sc[8], sh[8];
    if (useBn) {
        float4 s0 = *reinterpret_cast<const float4*>(bnscale + gc);
        float4 s1 = *reinterpret_cast<const float4*>(bnscale + gc + 4);
        float4 h0 = *reinterpret_cast<const float4*>(bnshift + gc);
        float4 h1 = *reinterpret_cast<const float4*>(bnshift + gc + 4);
        sc[0] = s0.x; sc[1] = s0.y; sc[2] = s0.z; sc[3] = s0.w;
        sc[4] = s1.x; sc[5] = s1.y; sc[6] = s1.z; sc[7] = s1.w;
        sh[0] = h0.x; sh[1] = h0.y; sh[2] = h0.z; sh[3] = h0.w;
        sh[4] = h1.x; sh[5] = h1.y; sh[6] = h1.z; sh[7] = h1.w;
    }

    int e0 = offs[n], e1 = offs[n + 1];
    float a0[8], a1[8];
#pragma unroll
    for (int i = 0; i < 8; ++i) { a0[i] = 0.f; a1[i] = 0.f; }

    int e = e0;
    for (; e + 2 <= e1; e += 2) {
        int s0i = csr[e], s1i = csr[e + 1];
        u16x8 v0 = *reinterpret_cast<const u16x8*>(XH + (size_t)s0i * 64 + c);
        u16x8 v1 = *reinterpret_cast<const u16x8*>(XH + (size_t)s1i * 64 + c);
        if (useBn) {
#pragma unroll
            for (int i = 0; i < 8; ++i) {
                a0[i] += fmaxf(bff((unsigned short)v0[i]) * sc[i] + sh[i], 0.f);
                a1[i] += fmaxf(bff((unsigned short)v1[i]) * sc[i] + sh[i], 0.f);
            }
        } else {
#pragma unroll
            for (int i = 0; i < 8; ++i) {
                a0[i] += bff((unsigned short)v0[i]);
                a1[i] += bff((unsigned short)v1[i]);
            }
        }
    }
    if (e < e1) {
        int s0i = csr[e];
        u16x8 v0 = *reinterpret_cast<const u16x8*>(XH + (size_t)s0i * 64 + c);
        if (useBn) {
#pragma unroll
            for (int i = 0; i < 8; ++i)
                a0[i] += fmaxf(bff((unsigned short)v0[i]) * sc[i] + sh[i], 0.f);
        } else {
#pragma unroll
            for (int i = 0; i < 8; ++i)
                a0[i] += bff((unsigned short)v0[i]);
        }
    }
    float id = invdeg[n];
    float4 o0 = {(a0[0] + a1[0]) * id, (a0[1] + a1[1]) * id,
                 (a0[2] + a1[2]) * id, (a0[3] + a1[3]) * id};
    float4 o1 = {(a0[4] + a1[4]) * id, (a0[5] + a1[5]) * id,
                 (a0[6] + a1[6]) * id, (a0[7] + a1[7]) * id};
    *reinterpret_cast<float4*>(HN + (size_t)n * D + gc) = o0;
    *reinterpret_cast<float4*>(HN + (size_t)n * D + gc + 4) = o1;
}

// ---------------- weight prep: transpose + split fp32 -> bf16 hi/lo ----------------
__global__ __launch_bounds__(256) void k_wprep(const float* __restrict__ W0,
                                               const float* __restrict__ W1,
                                               const float* __restrict__ W2,
                                               const float* __restrict__ W3,
                                               const float* __restrict__ W4,
                                               const float* __restrict__ W5,
                                               unsigned short* __restrict__ wt) {
    int mat = blockIdx.x >> 6;
    const float* srcs[6] = {W0, W1, W2, W3, W4, W5};
    const float* W = srcs[mat];
    int t = (blockIdx.x & 63) * 256 + threadIdx.x;
    int k = t >> 7;
    int n = t & 127;
    float w = W[k * 128 + n];
    uint32_t h = bfhi(w);
    uint32_t l = bfhi(w - bff(h));
    unsigned short* base = wt + (size_t)mat * 32768;
    base[n * 128 + k] = (unsigned short)h;
    base[16384 + n * 128 + k] = (unsigned short)l;
}

// ---------------- MFMA GEMM, zero-LDS zero-barrier ----------------
// 256 threads = 4 free-running waves. Block: 64 rows x 64 cols (col-half ch).
// Wave w: cols [ch*64 + w*16, +16). A-fragments loaded DIRECTLY from global
// (lane l reads row l&15, k=(l>>4)*8+kc*32 -> 16-32B contiguous), converted to
// split bf16 in registers. 4 independent acc chains (one per row-subtile).
__global__ __launch_bounds__(256, 3) void k_mm(const float* __restrict__ Xf,
                                               const unsigned short* __restrict__ Xhi,
                                               const unsigned short* __restrict__ Xlo,
                                               const float* __restrict__ HN,
                                               const unsigned short* __restrict__ WsT,
                                               const unsigned short* __restrict__ WnT,
                                               const float* __restrict__ bias,
                                               const float* __restrict__ bnscale,
                                               const float* __restrict__ bnshift,
                                               int mode,   // 0: Xf raw; 1: Xhi/Xlo + BN+ReLU
                                               float* __restrict__ OUTf,
                                               unsigned short* __restrict__ OUThi,
                                               unsigned short* __restrict__ OUTlo,
                                               int outFp32,
                                               int doStats,
                                               float* __restrict__ sums) {
    const int tid = threadIdx.x;
    const int lane = tid & 63;
    const int wave = tid >> 6;
    const int mlo = lane & 15;
    const int g = lane >> 4;
    const int ch = blockIdx.x & 1;
    const int row0 = (blockIdx.x >> 1) * 64;
    const int col = ch * 64 + wave * 16 + mlo;
    const float bcol = bias[col];

    f32x4 acc[4];
#pragma unroll
    for (int s = 0; s < 4; ++s) acc[s] = (f32x4){0.f, 0.f, 0.f, 0.f};

#pragma unroll
    for (int kc = 0; kc < 4; ++kc) {
        const int k0 = kc * 32 + g * 8;
        // B fragments for this k-chunk (L2-resident, reused by all blocks)
        bf16x8 wsh = *reinterpret_cast<const bf16x8*>(WsT + (size_t)col * 128 + k0);
        bf16x8 wsl = *reinterpret_cast<const bf16x8*>(WsT + 16384 + (size_t)col * 128 + k0);
        bf16x8 wnh = *reinterpret_cast<const bf16x8*>(WnT + (size_t)col * 128 + k0);
        bf16x8 wnl = *reinterpret_cast<const bf16x8*>(WnT + 16384 + (size_t)col * 128 + k0);

        float sc8[8], sh8[8];
        if (mode == 1) {
            float4 s0 = *reinterpret_cast<const float4*>(bnscale + k0);
            float4 s1 = *reinterpret_cast<const float4*>(bnscale + k0 + 4);
            float4 h0 = *reinterpret_cast<const float4*>(bnshift + k0);
            float4 h1 = *reinterpret_cast<const float4*>(bnshift + k0 + 4);
            sc8[0] = s0.x; sc8[1] = s0.y; sc8[2] = s0.z; sc8[3] = s0.w;
            sc8[4] = s1.x; sc8[5] = s1.y; sc8[6] = s1.z; sc8[7] = s1.w;
            sh8[0] = h0.x; sh8[1] = h0.y; sh8[2] = h0.z; sh8[3] = h0.w;
            sh8[4] = h1.x; sh8[5] = h1.y; sh8[6] = h1.z; sh8[7] = h1.w;
        }

#pragma unroll
        for (int s = 0; s < 4; ++s) {
            int row = row0 + s * 16 + mlo;
            float fx[8], fa[8];
            if (row < N_NODES) {
                const float* ap = HN + (size_t)row * D + k0;
                float4 a0 = *reinterpret_cast<const float4*>(ap);
                float4 a1 = *reinterpret_cast<const float4*>(ap + 4);
                fa[0] = a0.x; fa[1] = a0.y; fa[2] = a0.z; fa[3] = a0.w;
                fa[4] = a1.x; fa[5] = a1.y; fa[6] = a1.z; fa[7] = a1.w;
                if (mode == 0) {
                    const float* xp = Xf + (size_t)row * D + k0;
                    float4 x0 = *reinterpret_cast<const float4*>(xp);
                    float4 x1 = *reinterpret_cast<const float4*>(xp + 4);
                    fx[0] = x0.x; fx[1] = x0.y; fx[2] = x0.z; fx[3] = x0.w;
                    fx[4] = x1.x; fx[5] = x1.y; fx[6] = x1.z; fx[7] = x1.w;
                } else {
                    u16x8 hi = *reinterpret_cast<const u16x8*>(
                        Xhi + (size_t)(kc >> 1) * NHALF + (size_t)row * 64 + ((kc & 1) * 32 + g * 8));
                    u16x8 lo = *reinterpret_cast<const u16x8*>(Xlo + (size_t)row * D + k0);
#pragma unroll
                    for (int i = 0; i < 8; ++i) {
                        float v = bff((unsigned short)hi[i]) + bff((unsigned short)lo[i]);
                        fx[i] = fmaxf(v * sc8[i] + sh8[i], 0.f);
                    }
                }
            } else {
#pragma unroll
                for (int i = 0; i < 8; ++i) { fx[i] = 0.f; fa[i] = 0.f; }
            }
            bf16x8 xh, xl, ah, al;
#pragma unroll
            for (int i = 0; i < 8; ++i) {
                uint32_t h = bfhi(fx[i]);
                xh[i] = (short)h;
                xl[i] = (short)bfhi(fx[i] - bff(h));
                uint32_t ha = bfhi(fa[i]);
                ah[i] = (short)ha;
                al[i] = (short)bfhi(fa[i] - bff(ha));
            }
            acc[s] = __builtin_amdgcn_mfma_f32_16x16x32_bf16(xh, wsh, acc[s], 0, 0, 0);
            acc[s] = __builtin_amdgcn_mfma_f32_16x16x32_bf16(xh, wsl, acc[s], 0, 0, 0);
            acc[s] = __builtin_amdgcn_mfma_f32_16x16x32_bf16(xl, wsh, acc[s], 0, 0, 0);
            acc[s] = __builtin_amdgcn_mfma_f32_16x16x32_bf16(ah, wnh, acc[s], 0, 0, 0);
            acc[s] = __builtin_amdgcn_mfma_f32_16x16x32_bf16(ah, wnl, acc[s], 0, 0, 0);
            acc[s] = __builtin_amdgcn_mfma_f32_16x16x32_bf16(al, wnh, acc[s], 0, 0, 0);
        }
    }

    // ---- epilogue: bias, store, fused BN stats ----
    float cs = 0.f, cq = 0.f;
#pragma unroll
    for (int s = 0; s < 4; ++s) {
#pragma unroll
        for (int r = 0; r < 4; ++r) {
            int grow = row0 + s * 16 + g * 4 + r;
            if (grow < N_NODES) {
                float v = acc[s][r] + bcol;
                if (outFp32) {
                    OUTf[(size_t)grow * D + col] = v;
                } else {
                    uint32_t h = bfhi(v);
                    OUThi[(size_t)ch * NHALF + (size_t)grow * 64 + (col & 63)] = (unsigned short)h;
                    OUTlo[(size_t)grow * D + col] = (unsigned short)bfhi(v - bff(h));
                }
                cs += v; cq += v * v;
            }
        }
    }
    if (doStats) {
        cs += __shfl_xor(cs, 16); cs += __shfl_xor(cs, 32);
        cq += __shfl_xor(cq, 16); cq += __shfl_xor(cq, 32);
        if (lane < 16) {
            atomicAdd(&sums[col], cs);
            atomicAdd(&sums[128 + col], cq);
        }
    }
}

// ---------------- BN finalize: per-column scale/shift ----------------
__global__ void k_bnfin(const float* __restrict__ sums,
                        const float* __restrict__ gamma,
                        const float* __restrict__ beta,
                        float* __restrict__ scale,
                        float* __restrict__ shift) {
    int c = threadIdx.x;  // 128 threads
    const float invN = 1.0f / (float)N_NODES;
    float mu = sums[c] * invN;
    float var = sums[128 + c] * invN - mu * mu;
    float s = gamma[c] * rsqrtf(var + EPS);
    scale[c] = s;
    shift[c] = beta[c] - mu * s;
}

// ---------------- launch ----------------
extern "C" void kernel_launch(void* const* d_in, const int* in_sizes, int n_in,
                              void* d_out, int out_size, void* d_ws, size_t ws_size,
                              hipStream_t stream) {
    const float* x   = (const float*)d_in[0];
    const int*   src = (const int*)d_in[1];
    const int*   dst = (const int*)d_in[2];
    const float* Ws1 = (const float*)d_in[3];
    const float* Wn1 = (const float*)d_in[4];
    const float* b1  = (const float*)d_in[5];
    const float* g1  = (const float*)d_in[6];
    const float* be1 = (const float*)d_in[7];
    const float* Ws2 = (const float*)d_in[8];
    const float* Wn2 = (const float*)d_in[9];
    const float* b2  = (const float*)d_in[10];
    const float* g2  = (const float*)d_in[11];
    const float* be2 = (const float*)d_in[12];
    const float* Ws3 = (const float*)d_in[13];
    const float* Wn3 = (const float*)d_in[14];
    const float* b3  = (const float*)d_in[15];
    float* out = (float*)d_out;

    char* p = (char*)d_ws;
    auto alloc = [&](size_t bytes) -> char* {
        char* r = p;
        p += (bytes + 255) & ~(size_t)255;
        return r;
    };
    float* hn   = (float*)alloc((size_t)N_NODES * D * 4);
    unsigned short* xb   = (unsigned short*)alloc((size_t)N_NODES * D * 2);
    unsigned short* h1hi = (unsigned short*)alloc((size_t)N_NODES * D * 2);
    unsigned short* h1lo = (unsigned short*)alloc((size_t)N_NODES * D * 2);
    unsigned short* h2hi = (unsigned short*)alloc((size_t)N_NODES * D * 2);
    unsigned short* h2lo = (unsigned short*)alloc((size_t)N_NODES * D * 2);
    int*   csr    = (int*)alloc((size_t)NEDGE * 4);
    int*   offs   = (int*)alloc((size_t)(N_NODES + 1) * 4);
    int*   cursor = (int*)alloc((size_t)N_NODES * 4);
    int*   degi   = (int*)alloc((size_t)N_NODES * 4);
    float* invdeg = (float*)alloc((size_t)N_NODES * 4);
    int*   bsum   = (int*)alloc(1024);
    float* sums   = (float*)alloc(256 * 4);
    float* scale  = (float*)alloc(128 * 4);
    float* shift  = (float*)alloc(128 * 4);
    unsigned short* wt = (unsigned short*)alloc((size_t)6 * 32768 * 2);

    const int NB_E = (NEDGE + 255) / 256;
    const int NB_N = (N_NODES + 255) / 256;
    const int NB_A = 3128;                         // 2 halves x 1563 node-blocks (+guard)
    const int NB_M = 2 * ((N_NODES + 63) / 64);    // 2 col-halves x 782 row-groups
    const int NB_T = (N_NODES * D / 8 + 255) / 256;

    const unsigned short* WsT1 = wt + 0 * 32768;
    const unsigned short* WnT1 = wt + 1 * 32768;
    const unsigned short* WsT2 = wt + 2 * 32768;
    const unsigned short* WnT2 = wt + 3 * 32768;
    const unsigned short* WsT3 = wt + 4 * 32768;
    const unsigned short* WnT3 = wt + 5 * 32768;

    // ---- weight prep + CSR build + x->bf16 split planes (once) ----
    k_wprep<<<384, 256, 0, stream>>>(Ws1, Wn1, Ws2, Wn2, Ws3, Wn3, wt);
    hipMemsetAsync(degi, 0, (size_t)N_NODES * 4, stream);
    k_deg<<<NB_E, 256, 0, stream>>>(dst, degi);
    k_scan1<<<NB_N, 256, 0, stream>>>(degi, offs, bsum);
    k_scan2<<<1, 256, 0, stream>>>(bsum, NB_N);
    k_scan3<<<NB_N, 256, 0, stream>>>(degi, bsum, offs, cursor, invdeg);
    k_fill<<<NB_E, 256, 0, stream>>>(src, dst, cursor, csr);
    k_tobf16<<<NB_T, 256, 0, stream>>>(x, xb);

    // ---- Layer 1 ----
    k_agg<<<NB_A, 256, 0, stream>>>(xb, offs, csr, invdeg, scale, shift, 0, hn);
    hipMemsetAsync(sums, 0, 256 * 4, stream);
    k_mm<<<NB_M, 256, 0, stream>>>(x, h1hi, h1lo, hn, WsT1, WnT1, b1, scale, shift,
                                   0, out, h1hi, h1lo, 0, 1, sums);
    k_bnfin<<<1, 128, 0, stream>>>(sums, g1, be1, scale, shift);

    // ---- Layer 2 (BN1+ReLU applied on read) ----
    k_agg<<<NB_A, 256, 0, stream>>>(h1hi, offs, csr, invdeg, scale, shift, 1, hn);
    hipMemsetAsync(sums, 0, 256 * 4, stream);
    k_mm<<<NB_M, 256, 0, stream>>>(x, h1hi, h1lo, hn, WsT2, WnT2, b2, scale, shift,
                                   1, out, h2hi, h2lo, 0, 1, sums);
    k_bnfin<<<1, 128, 0, stream>>>(sums, g2, be2, scale, shift);

    // ---- Layer 3 (BN2+ReLU applied on read, fp32 out, no stats) ----
    k_agg<<<NB_A, 256, 0, stream>>>(h2hi, offs, csr, invdeg, scale, shift, 1, hn);
    k_mm<<<NB_M, 256, 0, stream>>>(x, h2hi, h2lo, hn, WsT3, WnT3, b3, scale, shift,
                                   1, out, h1hi, h1lo, 1, 0, sums);
}

// Round 7
// 511.523 us; speedup vs baseline: 1.0237x; 1.0237x over previous
//
#include <hip/hip_runtime.h>

#define N_NODES 50000
#define NEDGE   800000
#define D       128
#define EPS     1e-5f
#define NHALF   ((size_t)N_NODES * 64)

typedef __attribute__((ext_vector_type(8))) short bf16x8;
typedef __attribute__((ext_vector_type(4))) float f32x4;
typedef __attribute__((ext_vector_type(8))) unsigned short u16x8;

// fp32 -> bf16 (RNE) as ushort bits
__device__ inline uint32_t bfhi(float f) {
    uint32_t u = __float_as_uint(f);
    u += 0x7fffu + ((u >> 16) & 1u);
    return u >> 16;
}
__device__ inline float bff(uint32_t h) { return __uint_as_float(h << 16); }

// ---------------- degree count ----------------
__global__ __launch_bounds__(256) void k_deg(const int* __restrict__ dst,
                                             int* __restrict__ degi) {
    int e = blockIdx.x * 256 + threadIdx.x;
    if (e < NEDGE) atomicAdd(&degi[dst[e]], 1);
}

// ---------------- exclusive scan (3 kernels) ----------------
__global__ __launch_bounds__(256) void k_scan1(const int* __restrict__ degi,
                                               int* __restrict__ offs,
                                               int* __restrict__ bsum) {
    __shared__ int s[256];
    int tid = threadIdx.x;
    int i = blockIdx.x * 256 + tid;
    int v = (i < N_NODES) ? degi[i] : 0;
    s[tid] = v;
    __syncthreads();
    for (int d = 1; d < 256; d <<= 1) {
        int t = (tid >= d) ? s[tid - d] : 0;
        __syncthreads();
        s[tid] += t;
        __syncthreads();
    }
    if (i < N_NODES) offs[i] = s[tid] - v;   // exclusive
    if (tid == 255) bsum[blockIdx.x] = s[255];
}

__global__ __launch_bounds__(256) void k_scan2(int* __restrict__ bsum, int nb) {
    __shared__ int s[256];
    int tid = threadIdx.x;
    int v = (tid < nb) ? bsum[tid] : 0;
    s[tid] = v;
    __syncthreads();
    for (int d = 1; d < 256; d <<= 1) {
        int t = (tid >= d) ? s[tid - d] : 0;
        __syncthreads();
        s[tid] += t;
        __syncthreads();
    }
    if (tid < nb) bsum[tid] = s[tid] - v;    // exclusive block offsets
}

__global__ __launch_bounds__(256) void k_scan3(const int* __restrict__ degi,
                                               const int* __restrict__ bsum,
                                               int* __restrict__ offs,
                                               int* __restrict__ cursor,
                                               float* __restrict__ invdeg) {
    int i = blockIdx.x * 256 + threadIdx.x;
    if (i < N_NODES) {
        int o = offs[i] + bsum[blockIdx.x];
        offs[i] = o;
        cursor[i] = o;
        int dg = degi[i];
        invdeg[i] = 1.0f / (float)(dg > 0 ? dg : 1);
    }
    if (i == 0 && blockIdx.x == 0) offs[N_NODES] = NEDGE;
}

// ---------------- CSR bucket fill ----------------
__global__ __launch_bounds__(256) void k_fill(const int* __restrict__ src,
                                              const int* __restrict__ dst,
                                              int* __restrict__ cursor,
                                              int* __restrict__ csr) {
    int e = blockIdx.x * 256 + threadIdx.x;
    if (e < NEDGE) {
        int p = atomicAdd(&cursor[dst[e]], 1);
        csr[p] = src[e];
    }
}

// ---------------- fp32 -> bf16 hi+lo split planes [2][N][64] ----------------
__global__ __launch_bounds__(256) void k_tobf16(const float* __restrict__ X,
                                                unsigned short* __restrict__ XH,
                                                unsigned short* __restrict__ XL) {
    int t = blockIdx.x * 256 + threadIdx.x;
    if (t >= (N_NODES * D) / 8) return;
    int n = t >> 4;
    int c8 = (t & 15) * 8;
    const float* p = X + (size_t)n * D + c8;
    float4 a = *reinterpret_cast<const float4*>(p);
    float4 b = *reinterpret_cast<const float4*>(p + 4);
    float f[8] = {a.x, a.y, a.z, a.w, b.x, b.y, b.z, b.w};
    u16x8 oh, ol;
#pragma unroll
    for (int i = 0; i < 8; ++i) {
        uint32_t h = bfhi(f[i]);
        oh[i] = (unsigned short)h;
        ol[i] = (unsigned short)bfhi(f[i] - bff(h));
    }
    size_t off = (size_t)(c8 >> 6) * NHALF + (size_t)n * 64 + (c8 & 63);
    *reinterpret_cast<u16x8*>(XH + off) = oh;
    *reinterpret_cast<u16x8*>(XL + off) = ol;
}

// ---------------- BN+ReLU activation: h fp32 -> activated hi/lo planes ----------
__global__ __launch_bounds__(256) void k_act(const float* __restrict__ H,
                                             const float* __restrict__ scale,
                                             const float* __restrict__ shift,
                                             unsigned short* __restrict__ AH,
                                             unsigned short* __restrict__ AL) {
    int t = blockIdx.x * 256 + threadIdx.x;
    if (t >= (N_NODES * D) / 8) return;
    int n = t >> 4;
    int c8 = (t & 15) * 8;
    const float* p = H + (size_t)n * D + c8;
    float4 a = *reinterpret_cast<const float4*>(p);
    float4 b = *reinterpret_cast<const float4*>(p + 4);
    float4 s0 = *reinterpret_cast<const float4*>(scale + c8);
    float4 s1 = *reinterpret_cast<const float4*>(scale + c8 + 4);
    float4 h0 = *reinterpret_cast<const float4*>(shift + c8);
    float4 h1 = *reinterpret_cast<const float4*>(shift + c8 + 4);
    float f[8];
    f[0] = fmaxf(a.x * s0.x + h0.x, 0.f); f[1] = fmaxf(a.y * s0.y + h0.y, 0.f);
    f[2] = fmaxf(a.z * s0.z + h0.z, 0.f); f[3] = fmaxf(a.w * s0.w + h0.w, 0.f);
    f[4] = fmaxf(b.x * s1.x + h1.x, 0.f); f[5] = fmaxf(b.y * s1.y + h1.y, 0.f);
    f[6] = fmaxf(b.z * s1.z + h1.z, 0.f); f[7] = fmaxf(b.w * s1.w + h1.w, 0.f);
    u16x8 oh, ol;
#pragma unroll
    for (int i = 0; i < 8; ++i) {
        uint32_t h = bfhi(f[i]);
        oh[i] = (unsigned short)h;
        ol[i] = (unsigned short)bfhi(f[i] - bff(h));
    }
    size_t off = (size_t)(c8 >> 6) * NHALF + (size_t)n * 64 + (c8 & 63);
    *reinterpret_cast<u16x8*>(AH + off) = oh;
    *reinterpret_cast<u16x8*>(AL + off) = ol;
}

// ---------------- mean aggregation: gather hi half-plane, write hn hi/lo -------
// XCD-sharded: bit2 of bid selects half so (bid%8)->XCD round-robin pins each
// XCD to one 64-col half, halving per-XCD L2 fill. 32 nodes/block, 8 lanes/node.
__global__ __launch_bounds__(256) void k_agg(const unsigned short* __restrict__ AH,
                                             const int* __restrict__ offs,
                                             const int* __restrict__ csr,
                                             const float* __restrict__ invdeg,
                                             unsigned short* __restrict__ HNH,
                                             unsigned short* __restrict__ HNL) {
    int bid = blockIdx.x;
    int half = (bid >> 2) & 1;
    int nb = (bid >> 3) * 4 + (bid & 3);
    if (nb >= 1563) return;
    int n = nb * 32 + (threadIdx.x >> 3);
    if (n >= N_NODES) return;
    int c = (threadIdx.x & 7) * 8;        // col within half
    int gc = half * 64 + c;               // global col
    const unsigned short* XP = AH + (size_t)half * NHALF;

    int e0 = offs[n], e1 = offs[n + 1];
    float a0[8], a1[8];
#pragma unroll
    for (int i = 0; i < 8; ++i) { a0[i] = 0.f; a1[i] = 0.f; }

    int e = e0;
    for (; e + 2 <= e1; e += 2) {
        int s0i = csr[e], s1i = csr[e + 1];
        u16x8 v0 = *reinterpret_cast<const u16x8*>(XP + (size_t)s0i * 64 + c);
        u16x8 v1 = *reinterpret_cast<const u16x8*>(XP + (size_t)s1i * 64 + c);
#pragma unroll
        for (int i = 0; i < 8; ++i) {
            a0[i] += bff((unsigned short)v0[i]);
            a1[i] += bff((unsigned short)v1[i]);
        }
    }
    if (e < e1) {
        int s0i = csr[e];
        u16x8 v0 = *reinterpret_cast<const u16x8*>(XP + (size_t)s0i * 64 + c);
#pragma unroll
        for (int i = 0; i < 8; ++i)
            a0[i] += bff((unsigned short)v0[i]);
    }
    float id = invdeg[n];
    u16x8 oh, ol;
#pragma unroll
    for (int i = 0; i < 8; ++i) {
        float m = (a0[i] + a1[i]) * id;
        uint32_t h = bfhi(m);
        oh[i] = (unsigned short)h;
        ol[i] = (unsigned short)bfhi(m - bff(h));
    }
    *reinterpret_cast<u16x8*>(HNH + (size_t)n * D + gc) = oh;
    *reinterpret_cast<u16x8*>(HNL + (size_t)n * D + gc) = ol;
}

// ---------------- weight prep: transpose + split fp32 -> bf16 hi/lo ----------------
__global__ __launch_bounds__(256) void k_wprep(const float* __restrict__ W0,
                                               const float* __restrict__ W1,
                                               const float* __restrict__ W2,
                                               const float* __restrict__ W3,
                                               const float* __restrict__ W4,
                                               const float* __restrict__ W5,
                                               unsigned short* __restrict__ wt) {
    int mat = blockIdx.x >> 6;
    const float* srcs[6] = {W0, W1, W2, W3, W4, W5};
    const float* W = srcs[mat];
    int t = (blockIdx.x & 63) * 256 + threadIdx.x;
    int k = t >> 7;
    int n = t & 127;
    float w = W[k * 128 + n];
    uint32_t h = bfhi(w);
    uint32_t l = bfhi(w - bff(h));
    unsigned short* base = wt + (size_t)mat * 32768;
    base[n * 128 + k] = (unsigned short)h;
    base[16384 + n * 128 + k] = (unsigned short)l;
}

// ---------------- MFMA GEMM: pure-load, zero-LDS, zero-conversion ----------------
// 256 threads = 4 free-running waves; block = 64 rows x 64 cols (col-half ch).
// All operands are pre-split bf16 planes; lane loads its A-fragment (16B) direct
// from global (L1-shared across waves), 6 MFMAs per (kc,s). No barriers.
__global__ __launch_bounds__(256, 4) void k_mm(const unsigned short* __restrict__ XH,
                                               const unsigned short* __restrict__ XL,
                                               const unsigned short* __restrict__ HNH,
                                               const unsigned short* __restrict__ HNL,
                                               const unsigned short* __restrict__ WsT,
                                               const unsigned short* __restrict__ WnT,
                                               const float* __restrict__ bias,
                                               float* __restrict__ OUT,
                                               int doStats,
                                               float* __restrict__ sums) {
    const int tid = threadIdx.x;
    const int lane = tid & 63;
    const int wave = tid >> 6;
    const int mlo = lane & 15;
    const int g = lane >> 4;
    const int ch = blockIdx.x & 1;
    const int row0 = (blockIdx.x >> 1) * 64;
    const int col = ch * 64 + wave * 16 + mlo;
    const float bcol = bias[col];

    // weight fragments for all 4 k-chunks (64 VGPR)
    bf16x8 wsh[4], wsl[4], wnh[4], wnl[4];
#pragma unroll
    for (int kc = 0; kc < 4; ++kc) {
        int ko = kc * 32 + g * 8;
        wsh[kc] = *reinterpret_cast<const bf16x8*>(WsT + (size_t)col * 128 + ko);
        wsl[kc] = *reinterpret_cast<const bf16x8*>(WsT + 16384 + (size_t)col * 128 + ko);
        wnh[kc] = *reinterpret_cast<const bf16x8*>(WnT + (size_t)col * 128 + ko);
        wnl[kc] = *reinterpret_cast<const bf16x8*>(WnT + 16384 + (size_t)col * 128 + ko);
    }

    f32x4 acc[4];
#pragma unroll
    for (int s = 0; s < 4; ++s) acc[s] = (f32x4){0.f, 0.f, 0.f, 0.f};

#pragma unroll
    for (int kc = 0; kc < 4; ++kc) {
        const int k0 = kc * 32 + g * 8;
        const size_t xoff = (size_t)(kc >> 1) * NHALF + ((kc & 1) * 32 + g * 8);
#pragma unroll
        for (int s = 0; s < 4; ++s) {
            int row = row0 + s * 16 + mlo;
            u16x8 xh, xl, ah, al;
            if (row < N_NODES) {
                xh = *reinterpret_cast<const u16x8*>(XH + xoff + (size_t)row * 64);
                xl = *reinterpret_cast<const u16x8*>(XL + xoff + (size_t)row * 64);
                ah = *reinterpret_cast<const u16x8*>(HNH + (size_t)row * D + k0);
                al = *reinterpret_cast<const u16x8*>(HNL + (size_t)row * D + k0);
            } else {
                u16x8 z = {0, 0, 0, 0, 0, 0, 0, 0};
                xh = z; xl = z; ah = z; al = z;
            }
            bf16x8 bxh = *(bf16x8*)&xh, bxl = *(bf16x8*)&xl;
            bf16x8 bah = *(bf16x8*)&ah, bal = *(bf16x8*)&al;
            acc[s] = __builtin_amdgcn_mfma_f32_16x16x32_bf16(bxh, wsh[kc], acc[s], 0, 0, 0);
            acc[s] = __builtin_amdgcn_mfma_f32_16x16x32_bf16(bxh, wsl[kc], acc[s], 0, 0, 0);
            acc[s] = __builtin_amdgcn_mfma_f32_16x16x32_bf16(bxl, wsh[kc], acc[s], 0, 0, 0);
            acc[s] = __builtin_amdgcn_mfma_f32_16x16x32_bf16(bah, wnh[kc], acc[s], 0, 0, 0);
            acc[s] = __builtin_amdgcn_mfma_f32_16x16x32_bf16(bah, wnl[kc], acc[s], 0, 0, 0);
            acc[s] = __builtin_amdgcn_mfma_f32_16x16x32_bf16(bal, wnh[kc], acc[s], 0, 0, 0);
        }
    }

    // ---- epilogue: bias, store fp32, fused BN stats ----
    float cs = 0.f, cq = 0.f;
#pragma unroll
    for (int s = 0; s < 4; ++s) {
#pragma unroll
        for (int r = 0; r < 4; ++r) {
            int grow = row0 + s * 16 + g * 4 + r;
            if (grow < N_NODES) {
                float v = acc[s][r] + bcol;
                OUT[(size_t)grow * D + col] = v;
                cs += v; cq += v * v;
            }
        }
    }
    if (doStats) {
        cs += __shfl_xor(cs, 16); cs += __shfl_xor(cs, 32);
        cq += __shfl_xor(cq, 16); cq += __shfl_xor(cq, 32);
        if (lane < 16) {
            atomicAdd(&sums[col], cs);
            atomicAdd(&sums[128 + col], cq);
        }
    }
}

// ---------------- BN finalize: per-column scale/shift ----------------
__global__ void k_bnfin(const float* __restrict__ sums,
                        const float* __restrict__ gamma,
                        const float* __restrict__ beta,
                        float* __restrict__ scale,
                        float* __restrict__ shift) {
    int c = threadIdx.x;  // 128 threads
    const float invN = 1.0f / (float)N_NODES;
    float mu = sums[c] * invN;
    float var = sums[128 + c] * invN - mu * mu;
    float s = gamma[c] * rsqrtf(var + EPS);
    scale[c] = s;
    shift[c] = beta[c] - mu * s;
}

// ---------------- launch ----------------
extern "C" void kernel_launch(void* const* d_in, const int* in_sizes, int n_in,
                              void* d_out, int out_size, void* d_ws, size_t ws_size,
                              hipStream_t stream) {
    const float* x   = (const float*)d_in[0];
    const int*   src = (const int*)d_in[1];
    const int*   dst = (const int*)d_in[2];
    const float* Ws1 = (const float*)d_in[3];
    const float* Wn1 = (const float*)d_in[4];
    const float* b1  = (const float*)d_in[5];
    const float* g1  = (const float*)d_in[6];
    const float* be1 = (const float*)d_in[7];
    const float* Ws2 = (const float*)d_in[8];
    const float* Wn2 = (const float*)d_in[9];
    const float* b2  = (const float*)d_in[10];
    const float* g2  = (const float*)d_in[11];
    const float* be2 = (const float*)d_in[12];
    const float* Ws3 = (const float*)d_in[13];
    const float* Wn3 = (const float*)d_in[14];
    const float* b3  = (const float*)d_in[15];
    float* out = (float*)d_out;

    char* p = (char*)d_ws;
    auto alloc = [&](size_t bytes) -> char* {
        char* r = p;
        p += (bytes + 255) & ~(size_t)255;
        return r;
    };
    unsigned short* xph  = (unsigned short*)alloc((size_t)N_NODES * D * 2);
    unsigned short* xpl  = (unsigned short*)alloc((size_t)N_NODES * D * 2);
    unsigned short* aph  = (unsigned short*)alloc((size_t)N_NODES * D * 2);
    unsigned short* apl  = (unsigned short*)alloc((size_t)N_NODES * D * 2);
    unsigned short* hnh  = (unsigned short*)alloc((size_t)N_NODES * D * 2);
    unsigned short* hnl  = (unsigned short*)alloc((size_t)N_NODES * D * 2);
    float* hbuf   = (float*)alloc((size_t)N_NODES * D * 4);
    int*   csr    = (int*)alloc((size_t)NEDGE * 4);
    int*   offs   = (int*)alloc((size_t)(N_NODES + 1) * 4);
    int*   cursor = (int*)alloc((size_t)N_NODES * 4);
    int*   degi   = (int*)alloc((size_t)N_NODES * 4);
    float* invdeg = (float*)alloc((size_t)N_NODES * 4);
    int*   bsum   = (int*)alloc(1024);
    float* sums   = (float*)alloc(256 * 4);
    float* scale  = (float*)alloc(128 * 4);
    float* shift  = (float*)alloc(128 * 4);
    unsigned short* wt = (unsigned short*)alloc((size_t)6 * 32768 * 2);

    const int NB_E = (NEDGE + 255) / 256;
    const int NB_N = (N_NODES + 255) / 256;
    const int NB_A = 3128;                         // 2 halves x 1563 node-blocks
    const int NB_M = 2 * ((N_NODES + 63) / 64);    // 2 col-halves x 782 row-groups
    const int NB_T = (N_NODES * D / 8 + 255) / 256;

    const unsigned short* WsT1 = wt + 0 * 32768;
    const unsigned short* WnT1 = wt + 1 * 32768;
    const unsigned short* WsT2 = wt + 2 * 32768;
    const unsigned short* WnT2 = wt + 3 * 32768;
    const unsigned short* WsT3 = wt + 4 * 32768;
    const unsigned short* WnT3 = wt + 5 * 32768;

    // ---- weight prep + CSR build + x->split planes (once) ----
    k_wprep<<<384, 256, 0, stream>>>(Ws1, Wn1, Ws2, Wn2, Ws3, Wn3, wt);
    hipMemsetAsync(degi, 0, (size_t)N_NODES * 4, stream);
    k_deg<<<NB_E, 256, 0, stream>>>(dst, degi);
    k_scan1<<<NB_N, 256, 0, stream>>>(degi, offs, bsum);
    k_scan2<<<1, 256, 0, stream>>>(bsum, NB_N);
    k_scan3<<<NB_N, 256, 0, stream>>>(degi, bsum, offs, cursor, invdeg);
    k_fill<<<NB_E, 256, 0, stream>>>(src, dst, cursor, csr);
    k_tobf16<<<NB_T, 256, 0, stream>>>(x, xph, xpl);

    // ---- Layer 1 ----
    k_agg<<<NB_A, 256, 0, stream>>>(xph, offs, csr, invdeg, hnh, hnl);
    hipMemsetAsync(sums, 0, 256 * 4, stream);
    k_mm<<<NB_M, 256, 0, stream>>>(xph, xpl, hnh, hnl, WsT1, WnT1, b1,
                                   hbuf, 1, sums);
    k_bnfin<<<1, 128, 0, stream>>>(sums, g1, be1, scale, shift);
    k_act<<<NB_T, 256, 0, stream>>>(hbuf, scale, shift, aph, apl);

    // ---- Layer 2 ----
    k_agg<<<NB_A, 256, 0, stream>>>(aph, offs, csr, invdeg, hnh, hnl);
    hipMemsetAsync(sums, 0, 256 * 4, stream);
    k_mm<<<NB_M, 256, 0, stream>>>(aph, apl, hnh, hnl, WsT2, WnT2, b2,
                                   hbuf, 1, sums);
    k_bnfin<<<1, 128, 0, stream>>>(sums, g2, be2, scale, shift);
    k_act<<<NB_T, 256, 0, stream>>>(hbuf, scale, shift, aph, apl);

    // ---- Layer 3 (fp32 out, no stats) ----
    k_agg<<<NB_A, 256, 0, stream>>>(aph, offs, csr, invdeg, hnh, hnl);
    k_mm<<<NB_M, 256, 0, stream>>>(aph, apl, hnh, hnl, WsT3, WnT3, b3,
                                   out, 0, sums);
}

// Round 9
// 426.976 us; speedup vs baseline: 1.2265x; 1.1980x over previous
//
#include <hip/hip_runtime.h>

#define N_NODES 50000
#define NEDGE   800000
#define D       128
#define EPS     1e-5f
#define NT      3125                    // N_NODES/16 row-subtiles (exact)
#define NUNITS  800000                  // NT*4*64 16B-units per plane
#define NHALF   ((size_t)N_NODES * 64)

typedef __attribute__((ext_vector_type(8))) short bf16x8;
typedef __attribute__((ext_vector_type(4))) float f32x4;
typedef __attribute__((ext_vector_type(8))) unsigned short u16x8;

// fp32 -> bf16 (RNE) as ushort bits
__device__ inline uint32_t bfhi(float f) {
    uint32_t u = __float_as_uint(f);
    u += 0x7fffu + ((u >> 16) & 1u);
    return u >> 16;
}
__device__ inline float bff(uint32_t h) { return __uint_as_float(h << 16); }

// ---------------- degree count ----------------
__global__ __launch_bounds__(256) void k_deg(const int* __restrict__ dst,
                                             int* __restrict__ degi) {
    int e = blockIdx.x * 256 + threadIdx.x;
    if (e < NEDGE) atomicAdd(&degi[dst[e]], 1);
}

// ---------------- exclusive scan (3 kernels) ----------------
__global__ __launch_bounds__(256) void k_scan1(const int* __restrict__ degi,
                                               int* __restrict__ offs,
                                               int* __restrict__ bsum) {
    __shared__ int s[256];
    int tid = threadIdx.x;
    int i = blockIdx.x * 256 + tid;
    int v = (i < N_NODES) ? degi[i] : 0;
    s[tid] = v;
    __syncthreads();
    for (int d = 1; d < 256; d <<= 1) {
        int t = (tid >= d) ? s[tid - d] : 0;
        __syncthreads();
        s[tid] += t;
        __syncthreads();
    }
    if (i < N_NODES) offs[i] = s[tid] - v;   // exclusive
    if (tid == 255) bsum[blockIdx.x] = s[255];
}

__global__ __launch_bounds__(256) void k_scan2(int* __restrict__ bsum, int nb) {
    __shared__ int s[256];
    int tid = threadIdx.x;
    int v = (tid < nb) ? bsum[tid] : 0;
    s[tid] = v;
    __syncthreads();
    for (int d = 1; d < 256; d <<= 1) {
        int t = (tid >= d) ? s[tid - d] : 0;
        __syncthreads();
        s[tid] += t;
        __syncthreads();
    }
    if (tid < nb) bsum[tid] = s[tid] - v;    // exclusive block offsets
}

__global__ __launch_bounds__(256) void k_scan3(const int* __restrict__ degi,
                                               const int* __restrict__ bsum,
                                               int* __restrict__ offs,
                                               int* __restrict__ cursor,
                                               float* __restrict__ invdeg) {
    int i = blockIdx.x * 256 + threadIdx.x;
    if (i < N_NODES) {
        int o = offs[i] + bsum[blockIdx.x];
        offs[i] = o;
        cursor[i] = o;
        int dg = degi[i];
        invdeg[i] = 1.0f / (float)(dg > 0 ? dg : 1);
    }
    if (i == 0 && blockIdx.x == 0) offs[N_NODES] = NEDGE;
}

// ---------------- CSR bucket fill ----------------
__global__ __launch_bounds__(256) void k_fill(const int* __restrict__ src,
                                              const int* __restrict__ dst,
                                              int* __restrict__ cursor,
                                              int* __restrict__ csr) {
    int e = blockIdx.x * 256 + threadIdx.x;
    if (e < NEDGE) {
        int p = atomicAdd(&cursor[dst[e]], 1);
        csr[p] = src[e];
    }
}

// ---------------- x -> fragment-ordered hi/lo planes + half-split hi plane ------
// Fragment unit (t,kc,l) = rows 16t+(l&15), cols 32kc+8*(l>>4)..+8.
__global__ __launch_bounds__(256) void k_tobf16(const float* __restrict__ X,
                                                unsigned short* __restrict__ PH,
                                                unsigned short* __restrict__ PL,
                                                unsigned short* __restrict__ XG) {
    int flat = blockIdx.x * 256 + threadIdx.x;
    if (flat >= NUNITS) return;
    int tb = flat >> 8;
    int kc = (flat >> 6) & 3;
    int l = flat & 63;
    int row = tb * 16 + (l & 15);
    int col = kc * 32 + (l >> 4) * 8;
    const float* p = X + (size_t)row * D + col;
    float4 a = *reinterpret_cast<const float4*>(p);
    float4 b = *reinterpret_cast<const float4*>(p + 4);
    float f[8] = {a.x, a.y, a.z, a.w, b.x, b.y, b.z, b.w};
    u16x8 oh, ol;
#pragma unroll
    for (int i = 0; i < 8; ++i) {
        uint32_t h = bfhi(f[i]);
        oh[i] = (unsigned short)h;
        ol[i] = (unsigned short)bfhi(f[i] - bff(h));
    }
    *reinterpret_cast<u16x8*>(PH + (size_t)flat * 8) = oh;
    *reinterpret_cast<u16x8*>(PL + (size_t)flat * 8) = ol;
    *reinterpret_cast<u16x8*>(XG + (size_t)(col >> 6) * NHALF + (size_t)row * 64 + (col & 63)) = oh;
}

// ---------------- BN+ReLU: hbuf fp32 -> fragment planes + half-split hi plane ---
__global__ __launch_bounds__(256) void k_act(const float* __restrict__ H,
                                             const float* __restrict__ scale,
                                             const float* __restrict__ shift,
                                             unsigned short* __restrict__ PH,
                                             unsigned short* __restrict__ PL,
                                             unsigned short* __restrict__ XG) {
    int flat = blockIdx.x * 256 + threadIdx.x;
    if (flat >= NUNITS) return;
    int tb = flat >> 8;
    int kc = (flat >> 6) & 3;
    int l = flat & 63;
    int row = tb * 16 + (l & 15);
    int col = kc * 32 + (l >> 4) * 8;
    const float* p = H + (size_t)row * D + col;
    float4 a = *reinterpret_cast<const float4*>(p);
    float4 b = *reinterpret_cast<const float4*>(p + 4);
    float4 s0 = *reinterpret_cast<const float4*>(scale + col);
    float4 s1 = *reinterpret_cast<const float4*>(scale + col + 4);
    float4 h0 = *reinterpret_cast<const float4*>(shift + col);
    float4 h1 = *reinterpret_cast<const float4*>(shift + col + 4);
    float f[8];
    f[0] = fmaxf(a.x * s0.x + h0.x, 0.f); f[1] = fmaxf(a.y * s0.y + h0.y, 0.f);
    f[2] = fmaxf(a.z * s0.z + h0.z, 0.f); f[3] = fmaxf(a.w * s0.w + h0.w, 0.f);
    f[4] = fmaxf(b.x * s1.x + h1.x, 0.f); f[5] = fmaxf(b.y * s1.y + h1.y, 0.f);
    f[6] = fmaxf(b.z * s1.z + h1.z, 0.f); f[7] = fmaxf(b.w * s1.w + h1.w, 0.f);
    u16x8 oh, ol;
#pragma unroll
    for (int i = 0; i < 8; ++i) {
        uint32_t h = bfhi(f[i]);
        oh[i] = (unsigned short)h;
        ol[i] = (unsigned short)bfhi(f[i] - bff(h));
    }
    *reinterpret_cast<u16x8*>(PH + (size_t)flat * 8) = oh;
    *reinterpret_cast<u16x8*>(PL + (size_t)flat * 8) = ol;
    *reinterpret_cast<u16x8*>(XG + (size_t)(col >> 6) * NHALF + (size_t)row * 64 + (col & 63)) = oh;
}

// ---------------- mean aggregation: gather half-plane, write hn fragment planes -
// XCD-sharded by bit2 of bid (round-robin bid%8->XCD pins each XCD to one half).
// 32 nodes/block, 8 lanes/node (64 cols = 128B contiguous per gathered row).
__global__ __launch_bounds__(256) void k_agg(const unsigned short* __restrict__ XG,
                                             const int* __restrict__ offs,
                                             const int* __restrict__ csr,
                                             const float* __restrict__ invdeg,
                                             unsigned short* __restrict__ HNH,
                                             unsigned short* __restrict__ HNL) {
    int bid = blockIdx.x;
    int half = (bid >> 2) & 1;
    int nb = (bid >> 3) * 4 + (bid & 3);
    if (nb >= 1563) return;
    int n = nb * 32 + (threadIdx.x >> 3);
    if (n >= N_NODES) return;
    int c = (threadIdx.x & 7) * 8;        // col within half
    const unsigned short* XP = XG + (size_t)half * NHALF;

    int e0 = offs[n], e1 = offs[n + 1];
    float a0[8], a1[8];
#pragma unroll
    for (int i = 0; i < 8; ++i) { a0[i] = 0.f; a1[i] = 0.f; }

    int e = e0;
    for (; e + 2 <= e1; e += 2) {
        int s0i = csr[e], s1i = csr[e + 1];
        u16x8 v0 = *reinterpret_cast<const u16x8*>(XP + (size_t)s0i * 64 + c);
        u16x8 v1 = *reinterpret_cast<const u16x8*>(XP + (size_t)s1i * 64 + c);
#pragma unroll
        for (int i = 0; i < 8; ++i) {
            a0[i] += bff((unsigned short)v0[i]);
            a1[i] += bff((unsigned short)v1[i]);
        }
    }
    if (e < e1) {
        int s0i = csr[e];
        u16x8 v0 = *reinterpret_cast<const u16x8*>(XP + (size_t)s0i * 64 + c);
#pragma unroll
        for (int i = 0; i < 8; ++i)
            a0[i] += bff((unsigned short)v0[i]);
    }
    float id = invdeg[n];
    u16x8 oh, ol;
#pragma unroll
    for (int i = 0; i < 8; ++i) {
        float m = (a0[i] + a1[i]) * id;
        uint32_t h = bfhi(m);
        oh[i] = (unsigned short)h;
        ol[i] = (unsigned short)bfhi(m - bff(h));
    }
    int gc = half * 64 + c;
    int kc = gc >> 5;
    int l = (n & 15) + ((gc >> 3) & 3) * 16;
    size_t unit = ((size_t)(n >> 4) * 4 + kc) * 64 + l;
    *reinterpret_cast<u16x8*>(HNH + unit * 8) = oh;
    *reinterpret_cast<u16x8*>(HNL + unit * 8) = ol;
}

// ---------------- weight prep: transpose + split fp32 -> bf16 hi/lo ----------------
__global__ __launch_bounds__(256) void k_wprep(const float* __restrict__ W0,
                                               const float* __restrict__ W1,
                                               const float* __restrict__ W2,
                                               const float* __restrict__ W3,
                                               const float* __restrict__ W4,
                                               const float* __restrict__ W5,
                                               unsigned short* __restrict__ wt) {
    int mat = blockIdx.x >> 6;
    const float* srcs[6] = {W0, W1, W2, W3, W4, W5};
    const float* W = srcs[mat];
    int t = (blockIdx.x & 63) * 256 + threadIdx.x;
    int k = t >> 7;
    int n = t & 127;
    float w = W[k * 128 + n];
    uint32_t h = bfhi(w);
    uint32_t l = bfhi(w - bff(h));
    unsigned short* base = wt + (size_t)mat * 32768;
    base[n * 128 + k] = (unsigned short)h;
    base[16384 + n * 128 + k] = (unsigned short)l;
}

// ---------------- MFMA GEMM: fragment-ordered planes, fully coalesced -----------
// 256 threads = 4 free-running waves; block = 64 rows x 64 cols (col-half ch).
// Per (kc,s) a wave loads four CONTIGUOUS 1KB chunks (one per plane) + 6 MFMAs.
// No LDS, no barriers, no conversions.
__global__ __launch_bounds__(256, 4) void k_mm(const unsigned short* __restrict__ PH,
                                               const unsigned short* __restrict__ PL,
                                               const unsigned short* __restrict__ HNH,
                                               const unsigned short* __restrict__ HNL,
                                               const unsigned short* __restrict__ WsT,
                                               const unsigned short* __restrict__ WnT,
                                               const float* __restrict__ bias,
                                               float* __restrict__ OUT,
                                               int doStats,
                                               float* __restrict__ sums) {
    const int tid = threadIdx.x;
    const int lane = tid & 63;
    const int wave = tid >> 6;
    const int mlo = lane & 15;
    const int g = lane >> 4;
    const int ch = blockIdx.x & 1;
    const int t0 = (blockIdx.x >> 1) * 4;
    const int row0 = t0 * 16;
    const int col = ch * 64 + wave * 16 + mlo;
    const float bcol = bias[col];

    f32x4 acc[4];
#pragma unroll
    for (int s = 0; s < 4; ++s) acc[s] = (f32x4){0.f, 0.f, 0.f, 0.f};

#pragma unroll
    for (int kc = 0; kc < 4; ++kc) {
        int ko = kc * 32 + g * 8;
        bf16x8 wsh = *reinterpret_cast<const bf16x8*>(WsT + (size_t)col * 128 + ko);
        bf16x8 wsl = *reinterpret_cast<const bf16x8*>(WsT + 16384 + (size_t)col * 128 + ko);
        bf16x8 wnh = *reinterpret_cast<const bf16x8*>(WnT + (size_t)col * 128 + ko);
        bf16x8 wnl = *reinterpret_cast<const bf16x8*>(WnT + 16384 + (size_t)col * 128 + ko);
#pragma unroll
        for (int s = 0; s < 4; ++s) {
            int t = t0 + s;
            u16x8 xh, xl, ah, al;
            if (t < NT) {
                size_t idx = (((size_t)t * 4 + kc) * 64 + lane) * 8;
                xh = *reinterpret_cast<const u16x8*>(PH + idx);
                xl = *reinterpret_cast<const u16x8*>(PL + idx);
                ah = *reinterpret_cast<const u16x8*>(HNH + idx);
                al = *reinterpret_cast<const u16x8*>(HNL + idx);
            } else {
                u16x8 z = {0, 0, 0, 0, 0, 0, 0, 0};
                xh = z; xl = z; ah = z; al = z;
            }
            bf16x8 bxh = *(bf16x8*)&xh, bxl = *(bf16x8*)&xl;
            bf16x8 bah = *(bf16x8*)&ah, bal = *(bf16x8*)&al;
            acc[s] = __builtin_amdgcn_mfma_f32_16x16x32_bf16(bxh, wsh, acc[s], 0, 0, 0);
            acc[s] = __builtin_amdgcn_mfma_f32_16x16x32_bf16(bxh, wsl, acc[s], 0, 0, 0);
            acc[s] = __builtin_amdgcn_mfma_f32_16x16x32_bf16(bxl, wsh, acc[s], 0, 0, 0);
            acc[s] = __builtin_amdgcn_mfma_f32_16x16x32_bf16(bah, wnh, acc[s], 0, 0, 0);
            acc[s] = __builtin_amdgcn_mfma_f32_16x16x32_bf16(bah, wnl, acc[s], 0, 0, 0);
            acc[s] = __builtin_amdgcn_mfma_f32_16x16x32_bf16(bal, wnh, acc[s], 0, 0, 0);
        }
    }

    // ---- epilogue: bias, store fp32, fused BN stats ----
    float cs = 0.f, cq = 0.f;
#pragma unroll
    for (int s = 0; s < 4; ++s) {
#pragma unroll
        for (int r = 0; r < 4; ++r) {
            int grow = row0 + s * 16 + g * 4 + r;
            if (grow < N_NODES) {
                float v = acc[s][r] + bcol;
                OUT[(size_t)grow * D + col] = v;
                cs += v; cq += v * v;
            }
        }
    }
    if (doStats) {
        cs += __shfl_xor(cs, 16); cs += __shfl_xor(cs, 32);
        cq += __shfl_xor(cq, 16); cq += __shfl_xor(cq, 32);
        if (lane < 16) {
            atomicAdd(&sums[col], cs);
            atomicAdd(&sums[128 + col], cq);
        }
    }
}

// ---------------- BN finalize: per-column scale/shift ----------------
__global__ void k_bnfin(const float* __restrict__ sums,
                        const float* __restrict__ gamma,
                        const float* __restrict__ beta,
                        float* __restrict__ scale,
                        float* __restrict__ shift) {
    int c = threadIdx.x;  // 128 threads
    const float invN = 1.0f / (float)N_NODES;
    float mu = sums[c] * invN;
    float var = sums[128 + c] * invN - mu * mu;
    float s = gamma[c] * rsqrtf(var + EPS);
    scale[c] = s;
    shift[c] = beta[c] - mu * s;
}

// ---------------- launch ----------------
extern "C" void kernel_launch(void* const* d_in, const int* in_sizes, int n_in,
                              void* d_out, int out_size, void* d_ws, size_t ws_size,
                              hipStream_t stream) {
    const float* x   = (const float*)d_in[0];
    const int*   src = (const int*)d_in[1];
    const int*   dst = (const int*)d_in[2];
    const float* Ws1 = (const float*)d_in[3];
    const float* Wn1 = (const float*)d_in[4];
    const float* b1  = (const float*)d_in[5];
    const float* g1  = (const float*)d_in[6];
    const float* be1 = (const float*)d_in[7];
    const float* Ws2 = (const float*)d_in[8];
    const float* Wn2 = (const float*)d_in[9];
    const float* b2  = (const float*)d_in[10];
    const float* g2  = (const float*)d_in[11];
    const float* be2 = (const float*)d_in[12];
    const float* Ws3 = (const float*)d_in[13];
    const float* Wn3 = (const float*)d_in[14];
    const float* b3  = (const float*)d_in[15];
    float* out = (float*)d_out;

    char* p = (char*)d_ws;
    auto alloc = [&](size_t bytes) -> char* {
        char* r = p;
        p += (bytes + 255) & ~(size_t)255;
        return r;
    };
    unsigned short* pfh = (unsigned short*)alloc((size_t)NUNITS * 16);  // fragment hi
    unsigned short* pfl = (unsigned short*)alloc((size_t)NUNITS * 16);  // fragment lo
    unsigned short* xg  = (unsigned short*)alloc((size_t)N_NODES * D * 2); // half-split hi
    unsigned short* hnh = (unsigned short*)alloc((size_t)NUNITS * 16);
    unsigned short* hnl = (unsigned short*)alloc((size_t)NUNITS * 16);
    float* hbuf   = (float*)alloc((size_t)N_NODES * D * 4);
    int*   csr    = (int*)alloc((size_t)NEDGE * 4);
    int*   offs   = (int*)alloc((size_t)(N_NODES + 1) * 4);
    int*   cursor = (int*)alloc((size_t)N_NODES * 4);
    int*   degi   = (int*)alloc((size_t)N_NODES * 4);
    float* invdeg = (float*)alloc((size_t)N_NODES * 4);
    int*   bsum   = (int*)alloc(1024);
    float* sums   = (float*)alloc(256 * 4);
    float* scale  = (float*)alloc(128 * 4);
    float* shift  = (float*)alloc(128 * 4);
    unsigned short* wt = (unsigned short*)alloc((size_t)6 * 32768 * 2);

    const int NB_E = (NEDGE + 255) / 256;
    const int NB_N = (N_NODES + 255) / 256;
    const int NB_A = 3128;                         // 2 halves x 1563 node-blocks
    const int NB_M = 2 * ((N_NODES + 63) / 64);    // 2 col-halves x 782 row-groups
    const int NB_T = (NUNITS + 255) / 256;

    const unsigned short* WsT1 = wt + 0 * 32768;
    const unsigned short* WnT1 = wt + 1 * 32768;
    const unsigned short* WsT2 = wt + 2 * 32768;
    const unsigned short* WnT2 = wt + 3 * 32768;
    const unsigned short* WsT3 = wt + 4 * 32768;
    const unsigned short* WnT3 = wt + 5 * 32768;

    // ---- weight prep + CSR build + x->planes (once) ----
    k_wprep<<<384, 256, 0, stream>>>(Ws1, Wn1, Ws2, Wn2, Ws3, Wn3, wt);
    hipMemsetAsync(degi, 0, (size_t)N_NODES * 4, stream);
    k_deg<<<NB_E, 256, 0, stream>>>(dst, degi);
    k_scan1<<<NB_N, 256, 0, stream>>>(degi, offs, bsum);
    k_scan2<<<1, 256, 0, stream>>>(bsum, NB_N);
    k_scan3<<<NB_N, 256, 0, stream>>>(degi, bsum, offs, cursor, invdeg);
    k_fill<<<NB_E, 256, 0, stream>>>(src, dst, cursor, csr);
    k_tobf16<<<NB_T, 256, 0, stream>>>(x, pfh, pfl, xg);

    // ---- Layer 1 ----
    k_agg<<<NB_A, 256, 0, stream>>>(xg, offs, csr, invdeg, hnh, hnl);
    hipMemsetAsync(sums, 0, 256 * 4, stream);
    k_mm<<<NB_M, 256, 0, stream>>>(pfh, pfl, hnh, hnl, WsT1, WnT1, b1, hbuf, 1, sums);
    k_bnfin<<<1, 128, 0, stream>>>(sums, g1, be1, scale, shift);
    k_act<<<NB_T, 256, 0, stream>>>(hbuf, scale, shift, pfh, pfl, xg);

    // ---- Layer 2 ----
    k_agg<<<NB_A, 256, 0, stream>>>(xg, offs, csr, invdeg, hnh, hnl);
    hipMemsetAsync(sums, 0, 256 * 4, stream);
    k_mm<<<NB_M, 256, 0, stream>>>(pfh, pfl, hnh, hnl, WsT2, WnT2, b2, hbuf, 1, sums);
    k_bnfin<<<1, 128, 0, stream>>>(sums, g2, be2, scale, shift);
    k_act<<<NB_T, 256, 0, stream>>>(hbuf, scale, shift, pfh, pfl, xg);

    // ---- Layer 3 (fp32 out, no stats) ----
    k_agg<<<NB_A, 256, 0, stream>>>(xg, offs, csr, invdeg, hnh, hnl);
    k_mm<<<NB_M, 256, 0, stream>>>(pfh, pfl, hnh, hnl, WsT3, WnT3, b3, out, 0, sums);
}